// Round 2
// baseline (1669.756 us; speedup 1.0000x reference)
//
#include <hip/hip_runtime.h>

static constexpr int N = 100000;
static constexpr int E = 3200000;
static constexpr int NFEAT = 512;
static constexpr int K = 10;

// ---- workspace layout (bytes) ----
static constexpr size_t OFF_CNT    = 0;                              // N int
static constexpr size_t OFF_FILL   = 512ull * 1024;                  // N int
static constexpr size_t OFF_ROWPTR = 1024ull * 1024;                 // N+1 int
static constexpr size_t OFF_DINV   = 1536ull * 1024;                 // N float
static constexpr size_t OFF_BSUM   = 2048ull * 1024;                 // 128 int
static constexpr size_t OFF_EW     = 2560ull * 1024;                 // E int2 = 25.6 MB
static constexpr size_t OFF_HA     = OFF_EW + (size_t)E * 8 + 1024;  // N*64 f32
static constexpr size_t OFF_HB     = OFF_HA + (size_t)N * 64 * 4 + 1024;

// ---------- degree count ----------
__global__ __launch_bounds__(256) void count_k(const int* __restrict__ dst,
                                               int* __restrict__ cnt) {
  int e = blockIdx.x * 256 + threadIdx.x;
  if (e < E) atomicAdd(&cnt[dst[e]], 1);
}

__global__ __launch_bounds__(256) void dinv_k(const int* __restrict__ cnt,
                                              float* __restrict__ dinv) {
  int i = blockIdx.x * 256 + threadIdx.x;
  if (i < N) dinv[i] = 1.0f / sqrtf((float)(cnt[i] + 1));  // +1 self-loop
}

// ---------- exclusive scan (3 kernels) ----------
__device__ inline int wave_incl_scan(int x) {
  int lane = threadIdx.x & 63;
#pragma unroll
  for (int off = 1; off < 64; off <<= 1) {
    int y = __shfl_up(x, off, 64);
    if (lane >= off) x += y;
  }
  return x;
}

__global__ __launch_bounds__(256) void scan1_k(const int* __restrict__ cnt,
                                               int* __restrict__ rowptr,
                                               int* __restrict__ bsum) {
  __shared__ int wsum[4];
  int tid = threadIdx.x, wid = tid >> 6, lane = tid & 63;
  int base = blockIdx.x * 1024 + tid * 4;
  int4 v = {0, 0, 0, 0};
  if (base + 3 < N) {
    v = *(const int4*)(cnt + base);
  } else {
    if (base + 0 < N) v.x = cnt[base + 0];
    if (base + 1 < N) v.y = cnt[base + 1];
    if (base + 2 < N) v.z = cnt[base + 2];
    if (base + 3 < N) v.w = cnt[base + 3];
  }
  int tsum = v.x + v.y + v.z + v.w;
  int incl = wave_incl_scan(tsum);
  if (lane == 63) wsum[wid] = incl;
  __syncthreads();
  int wof = 0;
  for (int i = 0; i < wid; ++i) wof += wsum[i];
  int e0 = wof + incl - tsum;  // exclusive start for this thread
  if (base + 0 < N) rowptr[base + 0] = e0;
  if (base + 1 < N) rowptr[base + 1] = e0 + v.x;
  if (base + 2 < N) rowptr[base + 2] = e0 + v.x + v.y;
  if (base + 3 < N) rowptr[base + 3] = e0 + v.x + v.y + v.z;
  if (tid == 255) bsum[blockIdx.x] = wof + incl;  // block total
}

__global__ __launch_bounds__(128) void scan2_k(int* __restrict__ bsum) {
  __shared__ int w0sum;
  int tid = threadIdx.x, wid = tid >> 6, lane = tid & 63;
  int v = (tid < 98) ? bsum[tid] : 0;
  int incl = wave_incl_scan(v);
  if (wid == 0 && lane == 63) w0sum = incl;
  __syncthreads();
  int excl = incl - v + (wid ? w0sum : 0);
  if (tid < 98) bsum[tid] = excl;
}

__global__ __launch_bounds__(256) void scan3_k(int* __restrict__ rowptr,
                                               const int* __restrict__ bsum) {
  int i = blockIdx.x * 256 + threadIdx.x;
  if (i < N) rowptr[i] += bsum[blockIdx.x >> 2];
  if (i == 0) rowptr[N] = E;
}

// ---------- CSR fill ----------
__global__ __launch_bounds__(256) void fill_k(const int* __restrict__ src,
                                              const int* __restrict__ dst,
                                              const int* __restrict__ rowptr,
                                              int* __restrict__ fillc,
                                              const float* __restrict__ dinv,
                                              int2* __restrict__ ew) {
  int e = blockIdx.x * 256 + threadIdx.x;
  if (e >= E) return;
  int s = src[e], d = dst[e];
  int pos = rowptr[d] + atomicAdd(&fillc[d], 1);
  float w = dinv[s] * dinv[d];
  ew[pos] = make_int2(s, __float_as_int(w));
}

// ---------- GEMM1: h1 = relu(x @ W1 + b1), [N,512]x[512,64] ----------
__global__ __launch_bounds__(256) void gemm1_k(const float* __restrict__ x,
                                               const float* __restrict__ W1,
                                               const float* __restrict__ b1,
                                               float* __restrict__ h1) {
  __shared__ float xs[16][256];   // transposed x tile: xs[k][node]
  __shared__ float w1s[16 * 64];  // W1 tile
  const int tid = threadIdx.x;
  const int n0 = blockIdx.x * 256;
  const int tn = tid & 127;  // node pair: tn, tn+128
  const int jh = tid >> 7;   // j half: [jh*32, jh*32+32)
  float4 acca[8], accb[8];
#pragma unroll
  for (int i = 0; i < 8; ++i) {
    acca[i] = float4{0.f, 0.f, 0.f, 0.f};
    accb[i] = float4{0.f, 0.f, 0.f, 0.f};
  }
  const int rowA = min(n0 + tid, N - 1);
  const float* xr = x + (size_t)rowA * NFEAT;
  for (int k0 = 0; k0 < NFEAT; k0 += 16) {
    float4 a0 = *(const float4*)(xr + k0 + 0);
    float4 a1 = *(const float4*)(xr + k0 + 4);
    float4 a2 = *(const float4*)(xr + k0 + 8);
    float4 a3 = *(const float4*)(xr + k0 + 12);
    float4 wv = *(const float4*)(W1 + (size_t)k0 * 64 + tid * 4);
    __syncthreads();  // previous iteration's reads complete
    xs[0][tid] = a0.x;  xs[1][tid] = a0.y;  xs[2][tid] = a0.z;  xs[3][tid] = a0.w;
    xs[4][tid] = a1.x;  xs[5][tid] = a1.y;  xs[6][tid] = a1.z;  xs[7][tid] = a1.w;
    xs[8][tid] = a2.x;  xs[9][tid] = a2.y;  xs[10][tid] = a2.z; xs[11][tid] = a2.w;
    xs[12][tid] = a3.x; xs[13][tid] = a3.y; xs[14][tid] = a3.z; xs[15][tid] = a3.w;
    *(float4*)&w1s[tid * 4] = wv;
    __syncthreads();
#pragma unroll
    for (int kk = 0; kk < 16; ++kk) {
      float xa = xs[kk][tn];
      float xb = xs[kk][tn + 128];
      const float* wr = &w1s[kk * 64 + jh * 32];
#pragma unroll
      for (int jj = 0; jj < 8; ++jj) {
        float4 w4 = *(const float4*)(wr + jj * 4);
        acca[jj].x += xa * w4.x; acca[jj].y += xa * w4.y;
        acca[jj].z += xa * w4.z; acca[jj].w += xa * w4.w;
        accb[jj].x += xb * w4.x; accb[jj].y += xb * w4.y;
        accb[jj].z += xb * w4.z; accb[jj].w += xb * w4.w;
      }
    }
  }
  const int na = n0 + tn, nb = na + 128;
#pragma unroll
  for (int jj = 0; jj < 8; ++jj) {
    int j = jh * 32 + jj * 4;
    float4 bb = *(const float4*)(b1 + j);
    float4 ra, rb;
    ra.x = fmaxf(acca[jj].x + bb.x, 0.f); ra.y = fmaxf(acca[jj].y + bb.y, 0.f);
    ra.z = fmaxf(acca[jj].z + bb.z, 0.f); ra.w = fmaxf(acca[jj].w + bb.w, 0.f);
    rb.x = fmaxf(accb[jj].x + bb.x, 0.f); rb.y = fmaxf(accb[jj].y + bb.y, 0.f);
    rb.z = fmaxf(accb[jj].z + bb.z, 0.f); rb.w = fmaxf(accb[jj].w + bb.w, 0.f);
    if (na < N) *(float4*)(h1 + (size_t)na * 64 + j) = ra;
    if (nb < N) *(float4*)(h1 + (size_t)nb * 64 + j) = rb;
  }
}

// ---------- GEMM2: h0 = h1 @ W2 + b2 ; out = temp[0]*h0 ----------
__global__ __launch_bounds__(256) void gemm2_k(const float* __restrict__ h1,
                                               const float* __restrict__ W2,
                                               const float* __restrict__ b2,
                                               const float* __restrict__ temp,
                                               float* __restrict__ h0,
                                               float* __restrict__ out) {
  __shared__ float w2s[64 * 64];
  const int tid = threadIdx.x;
#pragma unroll
  for (int i = 0; i < 4; ++i)
    *(float4*)&w2s[(i * 256 + tid) * 4] = *(const float4*)(W2 + (size_t)(i * 256 + tid) * 4);
  __syncthreads();
  const int node = blockIdx.x * 256 + tid;
  if (node >= N) return;
  float4 acc[16];
#pragma unroll
  for (int c = 0; c < 16; ++c) acc[c] = *(const float4*)(b2 + c * 4);
  const float* hr = h1 + (size_t)node * 64;
  for (int j0 = 0; j0 < 64; j0 += 4) {
    float4 hv = *(const float4*)(hr + j0);
    float hv4[4] = {hv.x, hv.y, hv.z, hv.w};
#pragma unroll
    for (int l = 0; l < 4; ++l) {
      const float* wr = &w2s[(j0 + l) * 64];
#pragma unroll
      for (int c = 0; c < 16; ++c) {
        float4 w4 = *(const float4*)(wr + c * 4);
        acc[c].x += hv4[l] * w4.x; acc[c].y += hv4[l] * w4.y;
        acc[c].z += hv4[l] * w4.z; acc[c].w += hv4[l] * w4.w;
      }
    }
  }
  float t0 = temp[0];
  float* hp = h0 + (size_t)node * 64;
  float* op = out + (size_t)node * 64;
#pragma unroll
  for (int c = 0; c < 16; ++c) {
    *(float4*)(hp + c * 4) = acc[c];
    float4 o;
    o.x = t0 * acc[c].x; o.y = t0 * acc[c].y;
    o.z = t0 * acc[c].z; o.w = t0 * acc[c].w;
    *(float4*)(op + c * 4) = o;
  }
}

// ---------- propagation: hout = A_hat @ hin ; out += temp[kp1]*hout ----------
// 16 lanes per node (one float4 feature-quad per lane), 16 nodes per block.
// One global_load_dwordx4 per wave gathers 4 full rows (1 KB); 4-deep unroll
// keeps 4 KB in flight per wave.
__global__ __launch_bounds__(256) void prop_k(const float* __restrict__ hin,
                                              float* __restrict__ hout,
                                              float* __restrict__ out,
                                              const int* __restrict__ rowptr,
                                              const int2* __restrict__ ew,
                                              const float* __restrict__ dinv,
                                              const float* __restrict__ temp,
                                              int kp1, int writeh) {
  const int tid = threadIdx.x;
  const int sub = tid >> 4;  // node within block's 16
  const int q = tid & 15;    // feature quad: features [q*4, q*4+4)
  const int node = blockIdx.x * 16 + sub;  // N % 16 == 0, grid exact
  const int rs = rowptr[node];
  const int re = rowptr[node + 1];
  const float di = dinv[node];
  const float* __restrict__ hq = hin + q * 4;
  const int base = node * 64 + q * 4;

  // self-loop term
  float4 s = *(const float4*)(hq + node * 64);
  float w0 = di * di;
  float4 a0, a1, a2, a3;
  a0.x = w0 * s.x; a0.y = w0 * s.y; a0.z = w0 * s.z; a0.w = w0 * s.w;
  a1 = float4{0.f, 0.f, 0.f, 0.f};
  a2 = float4{0.f, 0.f, 0.f, 0.f};
  a3 = float4{0.f, 0.f, 0.f, 0.f};

  int e = rs;
  for (; e + 4 <= re; e += 4) {
    int2 p0 = ew[e], p1 = ew[e + 1], p2 = ew[e + 2], p3 = ew[e + 3];
    float4 r0 = *(const float4*)(hq + p0.x * 64);
    float4 r1 = *(const float4*)(hq + p1.x * 64);
    float4 r2 = *(const float4*)(hq + p2.x * 64);
    float4 r3 = *(const float4*)(hq + p3.x * 64);
    float w0f = __int_as_float(p0.y), w1f = __int_as_float(p1.y);
    float w2f = __int_as_float(p2.y), w3f = __int_as_float(p3.y);
    a0.x += w0f * r0.x; a0.y += w0f * r0.y; a0.z += w0f * r0.z; a0.w += w0f * r0.w;
    a1.x += w1f * r1.x; a1.y += w1f * r1.y; a1.z += w1f * r1.z; a1.w += w1f * r1.w;
    a2.x += w2f * r2.x; a2.y += w2f * r2.y; a2.z += w2f * r2.z; a2.w += w2f * r2.w;
    a3.x += w3f * r3.x; a3.y += w3f * r3.y; a3.z += w3f * r3.z; a3.w += w3f * r3.w;
  }
  for (; e < re; ++e) {
    int2 p = ew[e];
    float4 r = *(const float4*)(hq + p.x * 64);
    float wf = __int_as_float(p.y);
    a0.x += wf * r.x; a0.y += wf * r.y; a0.z += wf * r.z; a0.w += wf * r.w;
  }
  float4 acc;
  acc.x = (a0.x + a1.x) + (a2.x + a3.x);
  acc.y = (a0.y + a1.y) + (a2.y + a3.y);
  acc.z = (a0.z + a1.z) + (a2.z + a3.z);
  acc.w = (a0.w + a1.w) + (a2.w + a3.w);

  float t = temp[kp1];
  float4 o = *(const float4*)(out + base);
  o.x += t * acc.x; o.y += t * acc.y; o.z += t * acc.z; o.w += t * acc.w;
  *(float4*)(out + base) = o;
  if (writeh) *(float4*)(hout + base) = acc;
}

extern "C" void kernel_launch(void* const* d_in, const int* in_sizes, int n_in,
                              void* d_out, int out_size, void* d_ws, size_t ws_size,
                              hipStream_t stream) {
  const float* x = (const float*)d_in[0];
  const int* ei = (const int*)d_in[1];
  const float* W1 = (const float*)d_in[2];
  const float* b1 = (const float*)d_in[3];
  const float* W2 = (const float*)d_in[4];
  const float* b2 = (const float*)d_in[5];
  const float* temp = (const float*)d_in[6];
  const int* srcp = ei;       // edge_index[0]
  const int* dstp = ei + E;   // edge_index[1]

  unsigned char* ws = (unsigned char*)d_ws;
  int* cnt = (int*)(ws + OFF_CNT);
  int* fillc = (int*)(ws + OFF_FILL);
  int* rowptr = (int*)(ws + OFF_ROWPTR);
  float* dinv = (float*)(ws + OFF_DINV);
  int* bsum = (int*)(ws + OFF_BSUM);
  int2* ew = (int2*)(ws + OFF_EW);
  float* hA = (float*)(ws + OFF_HA);
  float* hB = (float*)(ws + OFF_HB);
  float* out = (float*)d_out;

  hipMemsetAsync(cnt, 0, (size_t)N * 4, stream);
  hipMemsetAsync(fillc, 0, (size_t)N * 4, stream);

  count_k<<<E / 256, 256, 0, stream>>>(dstp, cnt);
  dinv_k<<<(N + 255) / 256, 256, 0, stream>>>(cnt, dinv);
  scan1_k<<<(N + 1023) / 1024, 256, 0, stream>>>(cnt, rowptr, bsum);
  scan2_k<<<1, 128, 0, stream>>>(bsum);
  scan3_k<<<(N + 255) / 256, 256, 0, stream>>>(rowptr, bsum);
  fill_k<<<E / 256, 256, 0, stream>>>(srcp, dstp, rowptr, fillc, dinv, ew);

  gemm1_k<<<(N + 255) / 256, 256, 0, stream>>>(x, W1, b1, hB);
  gemm2_k<<<(N + 255) / 256, 256, 0, stream>>>(hB, W2, b2, temp, hA, out);

  const float* hin = hA;
  float* hout = hB;
  for (int k = 0; k < K; ++k) {
    prop_k<<<N / 16, 256, 0, stream>>>(hin, hout, out, rowptr, ew, dinv, temp,
                                       k + 1, (k + 1 < K) ? 1 : 0);
    float* t = (float*)hin;
    hin = hout;
    hout = t;
  }
}

// Round 3
// 1076.405 us; speedup vs baseline: 1.5512x; 1.5512x over previous
//
#include <hip/hip_runtime.h>

static constexpr int N = 100000;
static constexpr int E = 3200000;
static constexpr int NFEAT = 512;
static constexpr int K = 10;

typedef _Float16 half8 __attribute__((ext_vector_type(8)));
typedef _Float16 half4v __attribute__((ext_vector_type(4)));

// ---- workspace layout (bytes) ----
static constexpr size_t OFF_CNT    = 0;                               // N int
static constexpr size_t OFF_FILL   = 512ull * 1024;                   // N int
static constexpr size_t OFF_ROWPTR = 1024ull * 1024;                  // N+1 int
static constexpr size_t OFF_DINV   = 1536ull * 1024;                  // N float
static constexpr size_t OFF_BSUM   = 2048ull * 1024;                  // 128 int
static constexpr size_t OFF_EW     = 2560ull * 1024;                  // E int = 12.8 MB
static constexpr size_t OFF_GA     = OFF_EW + (size_t)E * 4 + 1024;   // N*64 fp16
static constexpr size_t OFF_GB     = OFF_GA + (size_t)N * 64 * 2 + 1024;
static constexpr size_t OFF_H1     = OFF_GB + (size_t)N * 64 * 2 + 1024;  // N*64 f32

// ---------- degree count ----------
__global__ __launch_bounds__(256) void count_k(const int* __restrict__ dst,
                                               int* __restrict__ cnt) {
  int e = blockIdx.x * 256 + threadIdx.x;
  if (e < E) atomicAdd(&cnt[dst[e]], 1);
}

__global__ __launch_bounds__(256) void dinv_k(const int* __restrict__ cnt,
                                              float* __restrict__ dinv) {
  int i = blockIdx.x * 256 + threadIdx.x;
  if (i < N) dinv[i] = 1.0f / sqrtf((float)(cnt[i] + 1));  // +1 self-loop
}

// ---------- exclusive scan (3 kernels) ----------
__device__ inline int wave_incl_scan(int x) {
  int lane = threadIdx.x & 63;
#pragma unroll
  for (int off = 1; off < 64; off <<= 1) {
    int y = __shfl_up(x, off, 64);
    if (lane >= off) x += y;
  }
  return x;
}

__global__ __launch_bounds__(256) void scan1_k(const int* __restrict__ cnt,
                                               int* __restrict__ rowptr,
                                               int* __restrict__ bsum) {
  __shared__ int wsum[4];
  int tid = threadIdx.x, wid = tid >> 6, lane = tid & 63;
  int base = blockIdx.x * 1024 + tid * 4;
  int4 v = {0, 0, 0, 0};
  if (base + 3 < N) {
    v = *(const int4*)(cnt + base);
  } else {
    if (base + 0 < N) v.x = cnt[base + 0];
    if (base + 1 < N) v.y = cnt[base + 1];
    if (base + 2 < N) v.z = cnt[base + 2];
    if (base + 3 < N) v.w = cnt[base + 3];
  }
  int tsum = v.x + v.y + v.z + v.w;
  int incl = wave_incl_scan(tsum);
  if (lane == 63) wsum[wid] = incl;
  __syncthreads();
  int wof = 0;
  for (int i = 0; i < wid; ++i) wof += wsum[i];
  int e0 = wof + incl - tsum;  // exclusive start for this thread
  if (base + 0 < N) rowptr[base + 0] = e0;
  if (base + 1 < N) rowptr[base + 1] = e0 + v.x;
  if (base + 2 < N) rowptr[base + 2] = e0 + v.x + v.y;
  if (base + 3 < N) rowptr[base + 3] = e0 + v.x + v.y + v.z;
  if (tid == 255) bsum[blockIdx.x] = wof + incl;  // block total
}

__global__ __launch_bounds__(128) void scan2_k(int* __restrict__ bsum) {
  __shared__ int w0sum;
  int tid = threadIdx.x, wid = tid >> 6, lane = tid & 63;
  int v = (tid < 98) ? bsum[tid] : 0;
  int incl = wave_incl_scan(v);
  if (wid == 0 && lane == 63) w0sum = incl;
  __syncthreads();
  int excl = incl - v + (wid ? w0sum : 0);
  if (tid < 98) bsum[tid] = excl;
}

__global__ __launch_bounds__(256) void scan3_k(int* __restrict__ rowptr,
                                               const int* __restrict__ bsum) {
  int i = blockIdx.x * 256 + threadIdx.x;
  if (i < N) rowptr[i] += bsum[blockIdx.x >> 2];
  if (i == 0) rowptr[N] = E;
}

// ---------- CSR fill, XCD-sliced ----------
// Each block owns one of 8 dst-slices (12.5k nodes -> ew slice of ~1.6MB,
// fits one XCD's 4MiB L2 so scattered 4B writes merge before HBM writeback).
// blockIdx&7 as the XCD id is a perf heuristic only (dispatch round-robins).
__global__ __launch_bounds__(256) void fill2_k(const int* __restrict__ src,
                                               const int* __restrict__ dst,
                                               const int* __restrict__ rowptr,
                                               int* __restrict__ fillc,
                                               int* __restrict__ ew) {
  const int slice = blockIdx.x & 7;
  const int chunk = blockIdx.x >> 3;
  const int lo = slice * 12500;
  const int hi = lo + 12500;  // N == 8*12500
  int e = chunk * 4096 + threadIdx.x;
  const int eend = min(E, chunk * 4096 + 4096);
  for (; e < eend; e += 256) {
    int d = dst[e];
    if (d >= lo && d < hi) {
      int pos = rowptr[d] + atomicAdd(&fillc[d], 1);
      ew[pos] = src[e];
    }
  }
}

// ---------- GEMM1: h1 = relu(x @ W1 + b1), [N,512]x[512,64] ----------
__global__ __launch_bounds__(256) void gemm1_k(const float* __restrict__ x,
                                               const float* __restrict__ W1,
                                               const float* __restrict__ b1,
                                               float* __restrict__ h1) {
  __shared__ float xs[16][256];   // transposed x tile: xs[k][node]
  __shared__ float w1s[16 * 64];  // W1 tile
  const int tid = threadIdx.x;
  const int n0 = blockIdx.x * 256;
  const int tn = tid & 127;  // node pair: tn, tn+128
  const int jh = tid >> 7;   // j half: [jh*32, jh*32+32)
  float4 acca[8], accb[8];
#pragma unroll
  for (int i = 0; i < 8; ++i) {
    acca[i] = float4{0.f, 0.f, 0.f, 0.f};
    accb[i] = float4{0.f, 0.f, 0.f, 0.f};
  }
  const int rowA = min(n0 + tid, N - 1);
  const float* xr = x + (size_t)rowA * NFEAT;
  for (int k0 = 0; k0 < NFEAT; k0 += 16) {
    float4 a0 = *(const float4*)(xr + k0 + 0);
    float4 a1 = *(const float4*)(xr + k0 + 4);
    float4 a2 = *(const float4*)(xr + k0 + 8);
    float4 a3 = *(const float4*)(xr + k0 + 12);
    float4 wv = *(const float4*)(W1 + (size_t)k0 * 64 + tid * 4);
    __syncthreads();  // previous iteration's reads complete
    xs[0][tid] = a0.x;  xs[1][tid] = a0.y;  xs[2][tid] = a0.z;  xs[3][tid] = a0.w;
    xs[4][tid] = a1.x;  xs[5][tid] = a1.y;  xs[6][tid] = a1.z;  xs[7][tid] = a1.w;
    xs[8][tid] = a2.x;  xs[9][tid] = a2.y;  xs[10][tid] = a2.z; xs[11][tid] = a2.w;
    xs[12][tid] = a3.x; xs[13][tid] = a3.y; xs[14][tid] = a3.z; xs[15][tid] = a3.w;
    *(float4*)&w1s[tid * 4] = wv;
    __syncthreads();
#pragma unroll
    for (int kk = 0; kk < 16; ++kk) {
      float xa = xs[kk][tn];
      float xb = xs[kk][tn + 128];
      const float* wr = &w1s[kk * 64 + jh * 32];
#pragma unroll
      for (int jj = 0; jj < 8; ++jj) {
        float4 w4 = *(const float4*)(wr + jj * 4);
        acca[jj].x += xa * w4.x; acca[jj].y += xa * w4.y;
        acca[jj].z += xa * w4.z; acca[jj].w += xa * w4.w;
        accb[jj].x += xb * w4.x; accb[jj].y += xb * w4.y;
        accb[jj].z += xb * w4.z; accb[jj].w += xb * w4.w;
      }
    }
  }
  const int na = n0 + tn, nb = na + 128;
#pragma unroll
  for (int jj = 0; jj < 8; ++jj) {
    int j = jh * 32 + jj * 4;
    float4 bb = *(const float4*)(b1 + j);
    float4 ra, rb;
    ra.x = fmaxf(acca[jj].x + bb.x, 0.f); ra.y = fmaxf(acca[jj].y + bb.y, 0.f);
    ra.z = fmaxf(acca[jj].z + bb.z, 0.f); ra.w = fmaxf(acca[jj].w + bb.w, 0.f);
    rb.x = fmaxf(accb[jj].x + bb.x, 0.f); rb.y = fmaxf(accb[jj].y + bb.y, 0.f);
    rb.z = fmaxf(accb[jj].z + bb.z, 0.f); rb.w = fmaxf(accb[jj].w + bb.w, 0.f);
    if (na < N) *(float4*)(h1 + (size_t)na * 64 + j) = ra;
    if (nb < N) *(float4*)(h1 + (size_t)nb * 64 + j) = rb;
  }
}

// ---------- GEMM2: h0 = h1@W2 + b2 ; out = temp[0]*h0 ; g0 = dinv*h0 (fp16) --
__global__ __launch_bounds__(256) void gemm2_k(const float* __restrict__ h1,
                                               const float* __restrict__ W2,
                                               const float* __restrict__ b2,
                                               const float* __restrict__ temp,
                                               const float* __restrict__ dinv,
                                               _Float16* __restrict__ g0,
                                               float* __restrict__ out) {
  __shared__ float w2s[64 * 64];
  const int tid = threadIdx.x;
#pragma unroll
  for (int i = 0; i < 4; ++i)
    *(float4*)&w2s[(i * 256 + tid) * 4] = *(const float4*)(W2 + (size_t)(i * 256 + tid) * 4);
  __syncthreads();
  const int node = blockIdx.x * 256 + tid;
  if (node >= N) return;
  float4 acc[16];
#pragma unroll
  for (int c = 0; c < 16; ++c) acc[c] = *(const float4*)(b2 + c * 4);
  const float* hr = h1 + (size_t)node * 64;
  for (int j0 = 0; j0 < 64; j0 += 4) {
    float4 hv = *(const float4*)(hr + j0);
    float hv4[4] = {hv.x, hv.y, hv.z, hv.w};
#pragma unroll
    for (int l = 0; l < 4; ++l) {
      const float* wr = &w2s[(j0 + l) * 64];
#pragma unroll
      for (int c = 0; c < 16; ++c) {
        float4 w4 = *(const float4*)(wr + c * 4);
        acc[c].x += hv4[l] * w4.x; acc[c].y += hv4[l] * w4.y;
        acc[c].z += hv4[l] * w4.z; acc[c].w += hv4[l] * w4.w;
      }
    }
  }
  const float t0 = temp[0];
  const float di = dinv[node];
  _Float16* gp = g0 + (size_t)node * 64;
  float* op = out + (size_t)node * 64;
#pragma unroll
  for (int c = 0; c < 16; ++c) {
    float4 o;
    o.x = t0 * acc[c].x; o.y = t0 * acc[c].y;
    o.z = t0 * acc[c].z; o.w = t0 * acc[c].w;
    *(float4*)(op + c * 4) = o;
    half4v g;
    g[0] = (_Float16)(di * acc[c].x); g[1] = (_Float16)(di * acc[c].y);
    g[2] = (_Float16)(di * acc[c].z); g[3] = (_Float16)(di * acc[c].w);
    *(half4v*)(gp + c * 4) = g;
  }
}

// ---------- propagation with prescaled fp16 state ----------
// g = dinv .* h. h'[i] = dinv[i]*(g[i] + sum_{src} g[src]);
// out += temp*h'; g' = dinv[i]*h'.
// 8 lanes per node (8 fp16 features/lane = 16B), 32 nodes per block.
__global__ __launch_bounds__(256) void prop_k(const _Float16* __restrict__ gin,
                                              _Float16* __restrict__ gout,
                                              float* __restrict__ out,
                                              const int* __restrict__ rowptr,
                                              const int* __restrict__ es,
                                              const float* __restrict__ dinv,
                                              const float* __restrict__ temp,
                                              int kp1, int writeh) {
  const int tid = threadIdx.x;
  const int sub = tid >> 3;                 // node within block's 32
  const int l = tid & 7;                    // feature octet [l*8, l*8+8)
  const int node = blockIdx.x * 32 + sub;   // N % 32 == 0, grid exact
  const int rs = rowptr[node];
  const int re = rowptr[node + 1];
  const float di = dinv[node];
  const _Float16* __restrict__ gq = gin + l * 8;

  // self term: + g[node]
  half8 sr = *(const half8*)(gq + (size_t)node * 64);
  float a0[8], a1[8], a2[8], a3[8];
#pragma unroll
  for (int i = 0; i < 8; ++i) {
    a0[i] = (float)sr[i];
    a1[i] = 0.f; a2[i] = 0.f; a3[i] = 0.f;
  }

  int e = rs;
  for (; e + 4 <= re; e += 4) {
    int s0 = es[e], s1 = es[e + 1], s2 = es[e + 2], s3 = es[e + 3];
    half8 r0 = *(const half8*)(gq + (size_t)s0 * 64);
    half8 r1 = *(const half8*)(gq + (size_t)s1 * 64);
    half8 r2 = *(const half8*)(gq + (size_t)s2 * 64);
    half8 r3 = *(const half8*)(gq + (size_t)s3 * 64);
#pragma unroll
    for (int i = 0; i < 8; ++i) {
      a0[i] += (float)r0[i];
      a1[i] += (float)r1[i];
      a2[i] += (float)r2[i];
      a3[i] += (float)r3[i];
    }
  }
  for (; e < re; ++e) {
    int s0 = es[e];
    half8 r0 = *(const half8*)(gq + (size_t)s0 * 64);
#pragma unroll
    for (int i = 0; i < 8; ++i) a0[i] += (float)r0[i];
  }

  float S[8];
#pragma unroll
  for (int i = 0; i < 8; ++i) S[i] = (a0[i] + a1[i]) + (a2[i] + a3[i]);

  const float th = temp[kp1] * di;  // out += temp * h' = temp * di * S
  const float dd = di * di;         // g' = di * h' = di*di * S
  const size_t base = (size_t)node * 64 + l * 8;
  float4 o0 = *(const float4*)(out + base);
  float4 o1 = *(const float4*)(out + base + 4);
  o0.x += th * S[0]; o0.y += th * S[1]; o0.z += th * S[2]; o0.w += th * S[3];
  o1.x += th * S[4]; o1.y += th * S[5]; o1.z += th * S[6]; o1.w += th * S[7];
  *(float4*)(out + base) = o0;
  *(float4*)(out + base + 4) = o1;
  if (writeh) {
    half8 gw;
#pragma unroll
    for (int i = 0; i < 8; ++i) gw[i] = (_Float16)(dd * S[i]);
    *(half8*)(gout + base) = gw;
  }
}

extern "C" void kernel_launch(void* const* d_in, const int* in_sizes, int n_in,
                              void* d_out, int out_size, void* d_ws, size_t ws_size,
                              hipStream_t stream) {
  const float* x = (const float*)d_in[0];
  const int* ei = (const int*)d_in[1];
  const float* W1 = (const float*)d_in[2];
  const float* b1 = (const float*)d_in[3];
  const float* W2 = (const float*)d_in[4];
  const float* b2 = (const float*)d_in[5];
  const float* temp = (const float*)d_in[6];
  const int* srcp = ei;       // edge_index[0]
  const int* dstp = ei + E;   // edge_index[1]

  unsigned char* ws = (unsigned char*)d_ws;
  int* cnt = (int*)(ws + OFF_CNT);
  int* fillc = (int*)(ws + OFF_FILL);
  int* rowptr = (int*)(ws + OFF_ROWPTR);
  float* dinv = (float*)(ws + OFF_DINV);
  int* bsum = (int*)(ws + OFF_BSUM);
  int* es = (int*)(ws + OFF_EW);
  _Float16* gA = (_Float16*)(ws + OFF_GA);
  _Float16* gB = (_Float16*)(ws + OFF_GB);
  float* h1 = (float*)(ws + OFF_H1);
  float* out = (float*)d_out;

  hipMemsetAsync(cnt, 0, (size_t)N * 4, stream);
  hipMemsetAsync(fillc, 0, (size_t)N * 4, stream);

  count_k<<<E / 256, 256, 0, stream>>>(dstp, cnt);
  dinv_k<<<(N + 255) / 256, 256, 0, stream>>>(cnt, dinv);
  scan1_k<<<(N + 1023) / 1024, 256, 0, stream>>>(cnt, rowptr, bsum);
  scan2_k<<<1, 128, 0, stream>>>(bsum);
  scan3_k<<<(N + 255) / 256, 256, 0, stream>>>(rowptr, bsum);
  fill2_k<<<8 * 782, 256, 0, stream>>>(srcp, dstp, rowptr, fillc, es);

  gemm1_k<<<(N + 255) / 256, 256, 0, stream>>>(x, W1, b1, h1);
  gemm2_k<<<(N + 255) / 256, 256, 0, stream>>>(h1, W2, b2, temp, dinv, gA, out);

  const _Float16* gin = gA;
  _Float16* gout = gB;
  for (int k = 0; k < K; ++k) {
    prop_k<<<N / 32, 256, 0, stream>>>(gin, gout, out, rowptr, es, dinv, temp,
                                       k + 1, (k + 1 < K) ? 1 : 0);
    _Float16* t = (_Float16*)gin;
    gin = gout;
    gout = t;
  }
}

// Round 4
// 1064.933 us; speedup vs baseline: 1.5679x; 1.0108x over previous
//
#include <hip/hip_runtime.h>

static constexpr int N = 100000;
static constexpr int E = 3200000;
static constexpr int NFEAT = 512;
static constexpr int K = 10;

typedef _Float16 half8 __attribute__((ext_vector_type(8)));
typedef _Float16 half4v __attribute__((ext_vector_type(4)));

// ---- workspace layout (bytes) ----
static constexpr size_t OFF_CNT    = 0;                               // N int
static constexpr size_t OFF_FILL   = 512ull * 1024;                   // N int
static constexpr size_t OFF_ROWPTR = 1024ull * 1024;                  // N+1 int
static constexpr size_t OFF_DINV   = 1536ull * 1024;                  // N float
static constexpr size_t OFF_BSUM   = 2048ull * 1024;                  // 128 int
static constexpr size_t OFF_EW     = 2560ull * 1024;                  // E int = 12.8 MB
static constexpr size_t OFF_GA     = OFF_EW + (size_t)E * 4 + 1024;   // N*64 fp16
static constexpr size_t OFF_GB     = OFF_GA + (size_t)N * 64 * 2 + 1024;
static constexpr size_t OFF_H1     = OFF_GB + (size_t)N * 64 * 2 + 1024;  // N*64 f32

// ---------- degree count ----------
__global__ __launch_bounds__(256) void count_k(const int* __restrict__ dst,
                                               int* __restrict__ cnt) {
  int e = blockIdx.x * 256 + threadIdx.x;
  if (e < E) atomicAdd(&cnt[__builtin_nontemporal_load(dst + e)], 1);
}

__global__ __launch_bounds__(256) void dinv_k(const int* __restrict__ cnt,
                                              float* __restrict__ dinv) {
  int i = blockIdx.x * 256 + threadIdx.x;
  if (i < N) dinv[i] = 1.0f / sqrtf((float)(cnt[i] + 1));  // +1 self-loop
}

// ---------- exclusive scan (3 kernels) ----------
__device__ inline int wave_incl_scan(int x) {
  int lane = threadIdx.x & 63;
#pragma unroll
  for (int off = 1; off < 64; off <<= 1) {
    int y = __shfl_up(x, off, 64);
    if (lane >= off) x += y;
  }
  return x;
}

__global__ __launch_bounds__(256) void scan1_k(const int* __restrict__ cnt,
                                               int* __restrict__ rowptr,
                                               int* __restrict__ bsum) {
  __shared__ int wsum[4];
  int tid = threadIdx.x, wid = tid >> 6, lane = tid & 63;
  int base = blockIdx.x * 1024 + tid * 4;
  int4 v = {0, 0, 0, 0};
  if (base + 3 < N) {
    v = *(const int4*)(cnt + base);
  } else {
    if (base + 0 < N) v.x = cnt[base + 0];
    if (base + 1 < N) v.y = cnt[base + 1];
    if (base + 2 < N) v.z = cnt[base + 2];
    if (base + 3 < N) v.w = cnt[base + 3];
  }
  int tsum = v.x + v.y + v.z + v.w;
  int incl = wave_incl_scan(tsum);
  if (lane == 63) wsum[wid] = incl;
  __syncthreads();
  int wof = 0;
  for (int i = 0; i < wid; ++i) wof += wsum[i];
  int e0 = wof + incl - tsum;  // exclusive start for this thread
  if (base + 0 < N) rowptr[base + 0] = e0;
  if (base + 1 < N) rowptr[base + 1] = e0 + v.x;
  if (base + 2 < N) rowptr[base + 2] = e0 + v.x + v.y;
  if (base + 3 < N) rowptr[base + 3] = e0 + v.x + v.y + v.z;
  if (tid == 255) bsum[blockIdx.x] = wof + incl;  // block total
}

__global__ __launch_bounds__(128) void scan2_k(int* __restrict__ bsum) {
  __shared__ int w0sum;
  int tid = threadIdx.x, wid = tid >> 6, lane = tid & 63;
  int v = (tid < 98) ? bsum[tid] : 0;
  int incl = wave_incl_scan(v);
  if (wid == 0 && lane == 63) w0sum = incl;
  __syncthreads();
  int excl = incl - v + (wid ? w0sum : 0);
  if (tid < 98) bsum[tid] = excl;
}

__global__ __launch_bounds__(256) void scan3_k(int* __restrict__ rowptr,
                                               const int* __restrict__ bsum) {
  int i = blockIdx.x * 256 + threadIdx.x;
  if (i < N) rowptr[i] += bsum[blockIdx.x >> 2];
  if (i == 0) rowptr[N] = E;
}

// ---------- CSR fill, XCD-sliced + non-temporal streaming reads ----------
// Each block owns one of 8 dst-slices (12.5k nodes -> ew slice of ~1.6MB in
// the owning XCD's 4MiB L2). The dst/src streams are read with the `nt`
// cache hint so they do NOT evict the dirty ew lines -> scattered 4B writes
// merge to full lines before HBM writeback.
__global__ __launch_bounds__(256) void fill2_k(const int* __restrict__ src,
                                               const int* __restrict__ dst,
                                               const int* __restrict__ rowptr,
                                               int* __restrict__ fillc,
                                               int* __restrict__ ew) {
  const int slice = blockIdx.x & 7;
  const int chunk = blockIdx.x >> 3;
  const int lo = slice * 12500;
  const int hi = lo + 12500;  // N == 8*12500
  int e = chunk * 4096 + threadIdx.x;
  const int eend = min(E, chunk * 4096 + 4096);
  for (; e < eend; e += 256) {
    int d = __builtin_nontemporal_load(dst + e);
    if (d >= lo && d < hi) {
      int pos = rowptr[d] + atomicAdd(&fillc[d], 1);
      ew[pos] = __builtin_nontemporal_load(src + e);
    }
  }
}

// ---------- GEMM1: h1 = relu(x @ W1 + b1), [N,512]x[512,64] ----------
__global__ __launch_bounds__(256) void gemm1_k(const float* __restrict__ x,
                                               const float* __restrict__ W1,
                                               const float* __restrict__ b1,
                                               float* __restrict__ h1) {
  __shared__ float xs[16][256];   // transposed x tile: xs[k][node]
  __shared__ float w1s[16 * 64];  // W1 tile
  const int tid = threadIdx.x;
  const int n0 = blockIdx.x * 256;
  const int tn = tid & 127;  // node pair: tn, tn+128
  const int jh = tid >> 7;   // j half: [jh*32, jh*32+32)
  float4 acca[8], accb[8];
#pragma unroll
  for (int i = 0; i < 8; ++i) {
    acca[i] = float4{0.f, 0.f, 0.f, 0.f};
    accb[i] = float4{0.f, 0.f, 0.f, 0.f};
  }
  const int rowA = min(n0 + tid, N - 1);
  const float* xr = x + (size_t)rowA * NFEAT;
  for (int k0 = 0; k0 < NFEAT; k0 += 16) {
    float4 a0 = *(const float4*)(xr + k0 + 0);
    float4 a1 = *(const float4*)(xr + k0 + 4);
    float4 a2 = *(const float4*)(xr + k0 + 8);
    float4 a3 = *(const float4*)(xr + k0 + 12);
    float4 wv = *(const float4*)(W1 + (size_t)k0 * 64 + tid * 4);
    __syncthreads();  // previous iteration's reads complete
    xs[0][tid] = a0.x;  xs[1][tid] = a0.y;  xs[2][tid] = a0.z;  xs[3][tid] = a0.w;
    xs[4][tid] = a1.x;  xs[5][tid] = a1.y;  xs[6][tid] = a1.z;  xs[7][tid] = a1.w;
    xs[8][tid] = a2.x;  xs[9][tid] = a2.y;  xs[10][tid] = a2.z; xs[11][tid] = a2.w;
    xs[12][tid] = a3.x; xs[13][tid] = a3.y; xs[14][tid] = a3.z; xs[15][tid] = a3.w;
    *(float4*)&w1s[tid * 4] = wv;
    __syncthreads();
#pragma unroll
    for (int kk = 0; kk < 16; ++kk) {
      float xa = xs[kk][tn];
      float xb = xs[kk][tn + 128];
      const float* wr = &w1s[kk * 64 + jh * 32];
#pragma unroll
      for (int jj = 0; jj < 8; ++jj) {
        float4 w4 = *(const float4*)(wr + jj * 4);
        acca[jj].x += xa * w4.x; acca[jj].y += xa * w4.y;
        acca[jj].z += xa * w4.z; acca[jj].w += xa * w4.w;
        accb[jj].x += xb * w4.x; accb[jj].y += xb * w4.y;
        accb[jj].z += xb * w4.z; accb[jj].w += xb * w4.w;
      }
    }
  }
  const int na = n0 + tn, nb = na + 128;
#pragma unroll
  for (int jj = 0; jj < 8; ++jj) {
    int j = jh * 32 + jj * 4;
    float4 bb = *(const float4*)(b1 + j);
    float4 ra, rb;
    ra.x = fmaxf(acca[jj].x + bb.x, 0.f); ra.y = fmaxf(acca[jj].y + bb.y, 0.f);
    ra.z = fmaxf(acca[jj].z + bb.z, 0.f); ra.w = fmaxf(acca[jj].w + bb.w, 0.f);
    rb.x = fmaxf(accb[jj].x + bb.x, 0.f); rb.y = fmaxf(accb[jj].y + bb.y, 0.f);
    rb.z = fmaxf(accb[jj].z + bb.z, 0.f); rb.w = fmaxf(accb[jj].w + bb.w, 0.f);
    if (na < N) *(float4*)(h1 + (size_t)na * 64 + j) = ra;
    if (nb < N) *(float4*)(h1 + (size_t)nb * 64 + j) = rb;
  }
}

// ---------- GEMM2: h0 = h1@W2 + b2 ; out = temp[0]*h0 ; g0 = dinv*h0 (fp16) --
__global__ __launch_bounds__(256) void gemm2_k(const float* __restrict__ h1,
                                               const float* __restrict__ W2,
                                               const float* __restrict__ b2,
                                               const float* __restrict__ temp,
                                               const float* __restrict__ dinv,
                                               _Float16* __restrict__ g0,
                                               float* __restrict__ out) {
  __shared__ float w2s[64 * 64];
  const int tid = threadIdx.x;
#pragma unroll
  for (int i = 0; i < 4; ++i)
    *(float4*)&w2s[(i * 256 + tid) * 4] = *(const float4*)(W2 + (size_t)(i * 256 + tid) * 4);
  __syncthreads();
  const int node = blockIdx.x * 256 + tid;
  if (node >= N) return;
  float4 acc[16];
#pragma unroll
  for (int c = 0; c < 16; ++c) acc[c] = *(const float4*)(b2 + c * 4);
  const float* hr = h1 + (size_t)node * 64;
  for (int j0 = 0; j0 < 64; j0 += 4) {
    float4 hv = *(const float4*)(hr + j0);
    float hv4[4] = {hv.x, hv.y, hv.z, hv.w};
#pragma unroll
    for (int l = 0; l < 4; ++l) {
      const float* wr = &w2s[(j0 + l) * 64];
#pragma unroll
      for (int c = 0; c < 16; ++c) {
        float4 w4 = *(const float4*)(wr + c * 4);
        acc[c].x += hv4[l] * w4.x; acc[c].y += hv4[l] * w4.y;
        acc[c].z += hv4[l] * w4.z; acc[c].w += hv4[l] * w4.w;
      }
    }
  }
  const float t0 = temp[0];
  const float di = dinv[node];
  _Float16* gp = g0 + (size_t)node * 64;
  float* op = out + (size_t)node * 64;
#pragma unroll
  for (int c = 0; c < 16; ++c) {
    float4 o;
    o.x = t0 * acc[c].x; o.y = t0 * acc[c].y;
    o.z = t0 * acc[c].z; o.w = t0 * acc[c].w;
    *(float4*)(op + c * 4) = o;
    half4v g;
    g[0] = (_Float16)(di * acc[c].x); g[1] = (_Float16)(di * acc[c].y);
    g[2] = (_Float16)(di * acc[c].z); g[3] = (_Float16)(di * acc[c].w);
    *(half4v*)(gp + c * 4) = g;
  }
}

// ---------- propagation with prescaled fp16 state ----------
// g = dinv .* h. h'[i] = dinv[i]*(g[i] + sum_{src} g[src]);
// out += temp*h'; g' = dinv[i]*h'.
// 8 lanes per node (8 fp16 features/lane = 16B), 32 nodes per block.
// 8-deep unrolled gather: 8 independent 1KB row-loads in flight per wave.
__global__ __launch_bounds__(256) void prop_k(const _Float16* __restrict__ gin,
                                              _Float16* __restrict__ gout,
                                              float* __restrict__ out,
                                              const int* __restrict__ rowptr,
                                              const int* __restrict__ es,
                                              const float* __restrict__ dinv,
                                              const float* __restrict__ temp,
                                              int kp1, int writeh) {
  const int tid = threadIdx.x;
  const int sub = tid >> 3;                 // node within block's 32
  const int l = tid & 7;                    // feature octet [l*8, l*8+8)
  const int node = blockIdx.x * 32 + sub;   // N % 32 == 0, grid exact
  const int rs = rowptr[node];
  const int re = rowptr[node + 1];
  const float di = dinv[node];
  const _Float16* __restrict__ gq = gin + l * 8;

  // self term: + g[node]
  half8 sr = *(const half8*)(gq + (size_t)node * 64);
  float a0[8], a1[8], a2[8], a3[8];
#pragma unroll
  for (int i = 0; i < 8; ++i) {
    a0[i] = (float)sr[i];
    a1[i] = 0.f; a2[i] = 0.f; a3[i] = 0.f;
  }

  int e = rs;
  for (; e + 8 <= re; e += 8) {
    int s0 = es[e],     s1 = es[e + 1], s2 = es[e + 2], s3 = es[e + 3];
    int s4 = es[e + 4], s5 = es[e + 5], s6 = es[e + 6], s7 = es[e + 7];
    half8 r0 = *(const half8*)(gq + (size_t)s0 * 64);
    half8 r1 = *(const half8*)(gq + (size_t)s1 * 64);
    half8 r2 = *(const half8*)(gq + (size_t)s2 * 64);
    half8 r3 = *(const half8*)(gq + (size_t)s3 * 64);
    half8 r4 = *(const half8*)(gq + (size_t)s4 * 64);
    half8 r5 = *(const half8*)(gq + (size_t)s5 * 64);
    half8 r6 = *(const half8*)(gq + (size_t)s6 * 64);
    half8 r7 = *(const half8*)(gq + (size_t)s7 * 64);
#pragma unroll
    for (int i = 0; i < 8; ++i) {
      a0[i] += (float)r0[i];
      a1[i] += (float)r1[i];
      a2[i] += (float)r2[i];
      a3[i] += (float)r3[i];
      a0[i] += (float)r4[i];
      a1[i] += (float)r5[i];
      a2[i] += (float)r6[i];
      a3[i] += (float)r7[i];
    }
  }
  for (; e + 4 <= re; e += 4) {
    int s0 = es[e], s1 = es[e + 1], s2 = es[e + 2], s3 = es[e + 3];
    half8 r0 = *(const half8*)(gq + (size_t)s0 * 64);
    half8 r1 = *(const half8*)(gq + (size_t)s1 * 64);
    half8 r2 = *(const half8*)(gq + (size_t)s2 * 64);
    half8 r3 = *(const half8*)(gq + (size_t)s3 * 64);
#pragma unroll
    for (int i = 0; i < 8; ++i) {
      a0[i] += (float)r0[i];
      a1[i] += (float)r1[i];
      a2[i] += (float)r2[i];
      a3[i] += (float)r3[i];
    }
  }
  for (; e < re; ++e) {
    int s0 = es[e];
    half8 r0 = *(const half8*)(gq + (size_t)s0 * 64);
#pragma unroll
    for (int i = 0; i < 8; ++i) a0[i] += (float)r0[i];
  }

  float S[8];
#pragma unroll
  for (int i = 0; i < 8; ++i) S[i] = (a0[i] + a1[i]) + (a2[i] + a3[i]);

  const float th = temp[kp1] * di;  // out += temp * h' = temp * di * S
  const float dd = di * di;         // g' = di * h' = di*di * S
  const size_t base = (size_t)node * 64 + l * 8;
  float4 o0 = *(const float4*)(out + base);
  float4 o1 = *(const float4*)(out + base + 4);
  o0.x += th * S[0]; o0.y += th * S[1]; o0.z += th * S[2]; o0.w += th * S[3];
  o1.x += th * S[4]; o1.y += th * S[5]; o1.z += th * S[6]; o1.w += th * S[7];
  *(float4*)(out + base) = o0;
  *(float4*)(out + base + 4) = o1;
  if (writeh) {
    half8 gw;
#pragma unroll
    for (int i = 0; i < 8; ++i) gw[i] = (_Float16)(dd * S[i]);
    *(half8*)(gout + base) = gw;
  }
}

extern "C" void kernel_launch(void* const* d_in, const int* in_sizes, int n_in,
                              void* d_out, int out_size, void* d_ws, size_t ws_size,
                              hipStream_t stream) {
  const float* x = (const float*)d_in[0];
  const int* ei = (const int*)d_in[1];
  const float* W1 = (const float*)d_in[2];
  const float* b1 = (const float*)d_in[3];
  const float* W2 = (const float*)d_in[4];
  const float* b2 = (const float*)d_in[5];
  const float* temp = (const float*)d_in[6];
  const int* srcp = ei;       // edge_index[0]
  const int* dstp = ei + E;   // edge_index[1]

  unsigned char* ws = (unsigned char*)d_ws;
  int* cnt = (int*)(ws + OFF_CNT);
  int* fillc = (int*)(ws + OFF_FILL);
  int* rowptr = (int*)(ws + OFF_ROWPTR);
  float* dinv = (float*)(ws + OFF_DINV);
  int* bsum = (int*)(ws + OFF_BSUM);
  int* es = (int*)(ws + OFF_EW);
  _Float16* gA = (_Float16*)(ws + OFF_GA);
  _Float16* gB = (_Float16*)(ws + OFF_GB);
  float* h1 = (float*)(ws + OFF_H1);
  float* out = (float*)d_out;

  hipMemsetAsync(cnt, 0, (size_t)N * 4, stream);
  hipMemsetAsync(fillc, 0, (size_t)N * 4, stream);

  count_k<<<E / 256, 256, 0, stream>>>(dstp, cnt);
  dinv_k<<<(N + 255) / 256, 256, 0, stream>>>(cnt, dinv);
  scan1_k<<<(N + 1023) / 1024, 256, 0, stream>>>(cnt, rowptr, bsum);
  scan2_k<<<1, 128, 0, stream>>>(bsum);
  scan3_k<<<(N + 255) / 256, 256, 0, stream>>>(rowptr, bsum);
  fill2_k<<<8 * 782, 256, 0, stream>>>(srcp, dstp, rowptr, fillc, es);

  gemm1_k<<<(N + 255) / 256, 256, 0, stream>>>(x, W1, b1, h1);
  gemm2_k<<<(N + 255) / 256, 256, 0, stream>>>(h1, W2, b2, temp, dinv, gA, out);

  const _Float16* gin = gA;
  _Float16* gout = gB;
  for (int k = 0; k < K; ++k) {
    prop_k<<<N / 32, 256, 0, stream>>>(gin, gout, out, rowptr, es, dinv, temp,
                                       k + 1, (k + 1 < K) ? 1 : 0);
    _Float16* t = (_Float16*)gin;
    gin = gout;
    gout = t;
  }
}